// Round 1
// baseline (438.396 us; speedup 1.0000x reference)
//
#include <hip/hip_runtime.h>
#include <stdint.h>

#define TT 2048
#define BB 4
#define HH 768
#define NHEADS 4
#define DD 768
#define NN 3072   // NHEADS*DD
#define LL 3
#define BT 8192   // BB*TT
#define KNB 5
#define NBLK 12   // 64-col partial blocks per head (DD/64)
#define ATPB 4    // tokens per attn block
#define NROWS 8   // ATPB + KNB - 1 (halo rows staged)

typedef __bf16 bf16x8 __attribute__((ext_vector_type(8)));
typedef float f32x4 __attribute__((ext_vector_type(4)));

__device__ __forceinline__ unsigned short f2bf(float f){
  union { float f; unsigned u; } v; v.f = f;
  unsigned u = v.u;
  return (unsigned short)((u + 0x7FFFu + ((u >> 16) & 1u)) >> 16);
}
__device__ __forceinline__ float bf2f(unsigned short h){
  union { unsigned u; float f; } v; v.u = ((unsigned)h) << 16;
  return v.f;
}
// async global->LDS, 16B per lane; LDS dest = wave-uniform base + lane*16
__device__ __forceinline__ void gload16(const unsigned short* g, unsigned short* l){
  __builtin_amdgcn_global_load_lds((const __attribute__((address_space(1))) void*)g,
                                   (__attribute__((address_space(3))) void*)l, 16, 0, 0);
}
__device__ __forceinline__ bf16x8 ld16(const unsigned short* p){
  return __builtin_bit_cast(bf16x8, *(const uint4*)p);
}
__device__ __forceinline__ void fencebar(){
  asm volatile("" ::: "memory");
  __builtin_amdgcn_s_barrier();
  asm volatile("" ::: "memory");
}

// ---------------- W transpose + bf16 convert: W[l][k][n] fp32 -> Wt[l][n][k] bf16
__global__ void wt_kernel(const float* __restrict__ W, unsigned short* __restrict__ Wt){
  __shared__ float tile[32][33];
  int l = blockIdx.z;
  int n0 = blockIdx.x * 32, k0 = blockIdx.y * 32;
  int tx = threadIdx.x, ty = threadIdx.y; // (32,8)
  const float* Wl = W + (size_t)l * HH * NN;
  for (int r = 0; r < 4; r++)
    tile[ty + r*8][tx] = Wl[(size_t)(k0 + ty + r*8) * NN + n0 + tx];
  __syncthreads();
  unsigned short* Wtl = Wt + (size_t)l * NN * HH;
  for (int r = 0; r < 4; r++){
    int n = n0 + ty + r*8;
    Wtl[(size_t)n * HH + k0 + tx] = f2bf(tile[tx][ty + r*8]);
  }
}

// ---------------- x fp32 -> bf16 (layer 0 GEMM input)
__global__ void xconv_kernel(const float* __restrict__ x, unsigned short* __restrict__ xb){
  int i = blockIdx.x * blockDim.x + threadIdx.x;
  float4 v = ((const float4*)x)[i];
  ushort4 o;
  o.x = f2bf(v.x); o.y = f2bf(v.y); o.z = f2bf(v.z); o.w = f2bf(v.w);
  *(ushort4*)(xb + (size_t)i * 4) = o;
}

// ---------------- GEMM: R12 — 256x256 tile, 8-wave, 4-phase/K-tile schedule
// (T3+T4 counted vmcnt: loads span barriers, never drained to 0 in steady
// state; T5 setprio around each 16-MFMA cluster; T2 chunk-XOR LDS swizzle
// kept from R6 — measured 0 bank conflicts). Per-wave vmem issue order per
// K-tile: B0,B1 | B2,B3 | Alo0,Alo1 | Ahi0,Ahi1 so vmcnt(2) at P3-end
// guarantees next tile's B + A-lo; vmcnt(2) after P0's MFMAs guarantees
// A-hi before P1 reads it. A-row<->issue map interleaved across waves so
// "A-lo" = exactly the rows all waves' phase-0 fragments touch.
#define BM 256
#define BN 256
#define BK 64
#define NKT (HH / BK)   // 12

__global__ __launch_bounds__(512, 2) void gemm_kernel(
    const unsigned short* __restrict__ xb,
    const unsigned short* __restrict__ wt,
    unsigned short* __restrict__ hout,
    const float* __restrict__ a_srcl,
    const float* __restrict__ a_dstl,
    float* __restrict__ psrc,     // [BT][NHEADS][NBLK]
    float* __restrict__ pdst){
  __shared__ __align__(16) unsigned short As[2][BM][BK];   // 64 KB
  __shared__ __align__(16) unsigned short Bs[2][BN][BK];   // 64 KB
  // bijective XCD swizzle (384 blocks = 8*48): per-XCD 4-row bm band,
  // bn-major within the band -> xb band (1.57 MB) L2-resident.
  int id = blockIdx.x;              // 384
  int xcd = id & 7;
  int s = id >> 3;                  // 0..47
  int bn_i = s >> 2;                // 0..11
  int bm_i = xcd * 4 + (s & 3);     // 0..31
  int bm = bm_i * BM;
  int bn = bn_i * BN;
  int tid = threadIdx.x;
  int wave = tid >> 6, lane = tid & 63;
  int m16 = lane & 15, q = lane >> 4;
  int wm = wave >> 2, wn = wave & 3;      // wave tile: rows wm*128, cols wn*64
  int r8 = lane >> 3, c8 = lane & 7;
  int cg = (c8 ^ r8) * 8;     // staged chunk: slot c8 holds global chunk c8^(row&7)

  const unsigned short* gA[4]; const unsigned short* gB[4];
  int arow[4], brow[4];
  #pragma unroll
  for (int ss = 0; ss < 4; ss++){
    int o = wave * 2 + (ss & 1);                     // 0..15
    arow[ss] = (ss >> 1) * 64 + o * 8 + ((o >= 8) ? 64 : 0);
    brow[ss] = wave * 32 + ss * 8;
    gA[ss] = xb + (size_t)(bm + arow[ss] + r8) * HH + cg;
    gB[ss] = wt + (size_t)(bn + brow[ss] + r8) * HH + cg;
  }
  int rd0 = ((0 + q) ^ (m16 & 7)) * 8;   // ks=0 fragment chunk offset (ushorts)
  int rd1 = ((4 + q) ^ (m16 & 7)) * 8;   // ks=1
  f32x4 acc[8][4] = {};

  // prologue: stage K-tile 0 into buf0 (issue order = steady-state order)
  #pragma unroll
  for (int ss = 0; ss < 4; ss++) gload16(gB[ss], &Bs[0][brow[ss]][0]);
  #pragma unroll
  for (int ss = 0; ss < 4; ss++) gload16(gA[ss], &As[0][arow[ss]][0]);
  asm volatile("s_waitcnt vmcnt(2)" ::: "memory");   // B + A-lo landed; A-hi in flight
  fencebar();

  #pragma unroll 2
  for (int kt = 0; kt < NKT; kt++){
    int cur = kt & 1, nxt = cur ^ 1;
    int koff = (kt + 1) * BK;
    bf16x8 af[4], bfv[4];
    // ---------- P0: mf 0..3, ks0 ----------
    #pragma unroll
    for (int i = 0; i < 4; i++)
      af[i] = ld16(&As[cur][wm*128 + i*16 + m16][rd0]);
    #pragma unroll
    for (int j = 0; j < 4; j++)
      bfv[j] = ld16(&Bs[cur][wn*64 + j*16 + m16][rd0]);
    if (kt < NKT-1){
      gload16(gB[0] + koff, &Bs[nxt][brow[0]][0]);
      gload16(gB[1] + koff, &Bs[nxt][brow[1]][0]);
    }
    fencebar();
    asm volatile("s_waitcnt lgkmcnt(0)" ::: "memory");
    __builtin_amdgcn_s_setprio(1);
    #pragma unroll
    for (int i = 0; i < 4; i++){
      #pragma unroll
      for (int j = 0; j < 4; j++)
        acc[i][j] = __builtin_amdgcn_mfma_f32_16x16x32_bf16(af[i], bfv[j], acc[i][j], 0, 0, 0);
    }
    __builtin_amdgcn_s_setprio(0);
    if (kt < NKT-1) { asm volatile("s_waitcnt vmcnt(2)" ::: "memory"); }  // A-hi of kt landed
    else            { asm volatile("s_waitcnt vmcnt(0)" ::: "memory"); }  // tail drain
    fencebar();
    // ---------- P1: mf 4..7, ks0 (B frags reused in regs) ----------
    #pragma unroll
    for (int i = 0; i < 4; i++)
      af[i] = ld16(&As[cur][wm*128 + 64 + i*16 + m16][rd0]);
    if (kt < NKT-1){
      gload16(gB[2] + koff, &Bs[nxt][brow[2]][0]);
      gload16(gB[3] + koff, &Bs[nxt][brow[3]][0]);
    }
    fencebar();
    asm volatile("s_waitcnt lgkmcnt(0)" ::: "memory");
    __builtin_amdgcn_s_setprio(1);
    #pragma unroll
    for (int i = 0; i < 4; i++){
      #pragma unroll
      for (int j = 0; j < 4; j++)
        acc[4+i][j] = __builtin_amdgcn_mfma_f32_16x16x32_bf16(af[i], bfv[j], acc[4+i][j], 0, 0, 0);
    }
    __builtin_amdgcn_s_setprio(0);
    fencebar();
    // ---------- P2: mf 0..3, ks1 ----------
    #pragma unroll
    for (int i = 0; i < 4; i++)
      af[i] = ld16(&As[cur][wm*128 + i*16 + m16][rd1]);
    #pragma unroll
    for (int j = 0; j < 4; j++)
      bfv[j] = ld16(&Bs[cur][wn*64 + j*16 + m16][rd1]);
    if (kt < NKT-1){
      gload16(gA[0] + koff, &As[nxt][arow[0]][0]);
      gload16(gA[1] + koff, &As[nxt][arow[1]][0]);
    }
    fencebar();
    asm volatile("s_waitcnt lgkmcnt(0)" ::: "memory");
    __builtin_amdgcn_s_setprio(1);
    #pragma unroll
    for (int i = 0; i < 4; i++){
      #pragma unroll
      for (int j = 0; j < 4; j++)
        acc[i][j] = __builtin_amdgcn_mfma_f32_16x16x32_bf16(af[i], bfv[j], acc[i][j], 0, 0, 0);
    }
    __builtin_amdgcn_s_setprio(0);
    fencebar();
    // ---------- P3: mf 4..7, ks1 ----------
    #pragma unroll
    for (int i = 0; i < 4; i++)
      af[i] = ld16(&As[cur][wm*128 + 64 + i*16 + m16][rd1]);
    if (kt < NKT-1){
      gload16(gA[2] + koff, &As[nxt][arow[2]][0]);
      gload16(gA[3] + koff, &As[nxt][arow[3]][0]);
    }
    fencebar();
    asm volatile("s_waitcnt lgkmcnt(0)" ::: "memory");
    __builtin_amdgcn_s_setprio(1);
    #pragma unroll
    for (int i = 0; i < 4; i++){
      #pragma unroll
      for (int j = 0; j < 4; j++)
        acc[4+i][j] = __builtin_amdgcn_mfma_f32_16x16x32_bf16(af[i], bfv[j], acc[4+i][j], 0, 0, 0);
    }
    __builtin_amdgcn_s_setprio(0);
    if (kt < NKT-1) { asm volatile("s_waitcnt vmcnt(2)" ::: "memory"); }  // kt+1 B + A-lo landed
    fencebar();
  }

  // C store (bf16) — wave tile rows bm+wm*128+.., cols bn+wn*64+..
  #pragma unroll
  for (int i = 0; i < 8; i++){
    int row0 = bm + wm*128 + i*16 + q*4;
    #pragma unroll
    for (int j = 0; j < 4; j++){
      int col = bn + wn*64 + j*16 + m16;
      unsigned short* hp = hout + (size_t)row0 * NN + col;
      hp[0]            = f2bf(acc[i][j][0]);
      hp[NN]           = f2bf(acc[i][j][1]);
      hp[2*(size_t)NN] = f2bf(acc[i][j][2]);
      hp[3*(size_t)NN] = f2bf(acc[i][j][3]);
    }
  }
  // fused asrc/adst partials: wave covers 64 cols = one (head, blk) slot
  int col0 = bn + wn*64;
  int head = col0 / DD;
  int blk  = (col0 % DD) >> 6;
  float wsrc[4], wdstw[4];
  #pragma unroll
  for (int j = 0; j < 4; j++){
    int n = col0 + j*16 + m16;
    wsrc[j]  = a_srcl[n];
    wdstw[j] = a_dstl[n];
  }
  #pragma unroll
  for (int i = 0; i < 8; i++){
    #pragma unroll
    for (int reg = 0; reg < 4; reg++){
      float ss = 0.f, dd = 0.f;
      #pragma unroll
      for (int j = 0; j < 4; j++){
        float v = acc[i][j][reg];
        ss += v * wsrc[j];
        dd += v * wdstw[j];
      }
      ss += __shfl_xor(ss, 1, 64); dd += __shfl_xor(dd, 1, 64);
      ss += __shfl_xor(ss, 2, 64); dd += __shfl_xor(dd, 2, 64);
      ss += __shfl_xor(ss, 4, 64); dd += __shfl_xor(dd, 4, 64);
      ss += __shfl_xor(ss, 8, 64); dd += __shfl_xor(dd, 8, 64);
      if (m16 == 0){
        int row = bm + wm*128 + i*16 + q*4 + reg;
        size_t slot = (size_t)row * (NHEADS * NBLK) + head * NBLK + blk;
        psrc[slot] = ss;
        pdst[slot] = dd;
      }
    }
  }
}

// ---------------- attention + head-mean + bias + residual + layernorm
// R10 structure; R11: hs-independent global loads (residual, bias, gamma,
// beta) hoisted before the DMA-drain barrier to overlap staging latency.
__global__ __launch_bounds__(384) void attn_ln_kernel(const unsigned short* __restrict__ h,
    const float* __restrict__ psrc, const float* __restrict__ pdst,
    const float* __restrict__ xin_f32,          // non-null => layer 0 residual (fp32)
    const unsigned short* __restrict__ xin_bf,  // else residual from bf16 xb
    const float* __restrict__ bias_l,
    const float* __restrict__ gamma_l, const float* __restrict__ beta_l,
    float* __restrict__ x_out, unsigned short* __restrict__ xb_next,
    int write_f32){
  int bid = blockIdx.x;                       // 2048
  int grp = ((bid & 7) << 8) | (bid >> 3);    // XCD-contiguous groups
  int token0 = grp * ATPB;
  int t0 = token0 & (TT - 1);
  int bseq = token0 >> 11;
  int tid = threadIdx.x;
  int wave = tid >> 6, lane = tid & 63;
  int ti = tid / 96, c = tid % 96;            // token-in-block, 8-elem chunk
  int token = token0 + ti;
  __shared__ __align__(16) unsigned short hs[NROWS][NN];   // 48 KB
  __shared__ float attn_s[ATPB][NHEADS][KNB];
  __shared__ float as_sh[NROWS * NHEADS], ad_sh[NROWS * NHEADS];
  __shared__ float part_s[ATPB * 96], part_q[ATPB * 96];
  __shared__ float mv_mean[ATPB], mv_rstd[ATPB];
  // stage 8 clamped rows via async DMA (issues immediately, drains at barrier)
  #pragma unroll
  for (int j = 0; j < NROWS; j++){
    int g = t0 - 2 + j;
    g = min(max(g, 0), TT - 1);
    const unsigned short* src = h + ((size_t)(bseq * TT + g)) * NN + tid * 8;
    gload16(src, &hs[j][wave * 512]);
  }
  // hoisted hs-independent loads: overlap DMA drain
  float xr[8], bb[8], gr[8], br[8];
  if (xin_f32){
    const float4* p = (const float4*)&xin_f32[(size_t)token * HH + c * 8];
    *(float4*)&xr[0] = p[0]; *(float4*)&xr[4] = p[1];
  } else {
    uint4 u = *(const uint4*)&xin_bf[(size_t)token * HH + c * 8];
    const unsigned short* us = (const unsigned short*)&u;
    #pragma unroll
    for (int e = 0; e < 8; e++) xr[e] = bf2f(us[e]);
  }
  { const float4* p = (const float4*)&bias_l[c * 8];
    *(float4*)&bb[0] = p[0]; *(float4*)&bb[4] = p[1]; }
  { const float4* p = (const float4*)&gamma_l[c * 8];
    *(float4*)&gr[0] = p[0]; *(float4*)&gr[4] = p[1]; }
  { const float4* p = (const float4*)&beta_l[c * 8];
    *(float4*)&br[0] = p[0]; *(float4*)&br[4] = p[1]; }
  // fused srcred: 64 threads sum the halo tokens' partials into LDS
  if (tid < 2 * NROWS * NHEADS){     // 64
    int which = tid >= NROWS * NHEADS;
    int i = tid & (NROWS * NHEADS - 1);
    int lt = i >> 2, head = i & 3;
    int tcl = min(max(t0 - 2 + lt, 0), TT - 1);
    const float* p = (which ? pdst : psrc) +
        ((size_t)(bseq * TT + tcl) * NHEADS + head) * NBLK;
    float4 a = *(const float4*)(p);
    float4 b = *(const float4*)(p + 4);
    float4 d = *(const float4*)(p + 8);
    float s = a.x+a.y+a.z+a.w + b.x+b.y+b.z+b.w + d.x+d.y+d.z+d.w;
    (which ? ad_sh : as_sh)[i] = s;
  }
  __syncthreads();
  if (tid < ATPB * NHEADS){          // 16: per-(token,head) softmax
    int tii = tid >> 2, head = tid & 3;
    int t = t0 + tii;
    float sc[KNB];
    float mx = -3.0e38f;
    float ad = ad_sh[(tii + 2) * NHEADS + head];
    for (int k = 0; k < KNB; k++){
      int tn = t + k - 2;
      if (tn >= 0 && tn < TT){
        float s = as_sh[(tii + k) * NHEADS + head] + ad;
        s = s > 0.f ? s : 0.2f * s;       // leaky_relu 0.2
        sc[k] = s; mx = fmaxf(mx, s);
      } else sc[k] = -3.0e38f;
    }
    float den = 0.f;
    for (int k = 0; k < KNB; k++){
      float e = (sc[k] > -1.0e38f) ? __expf(sc[k] - mx) : 0.f;
      sc[k] = e; den += e;
    }
    float inv = 0.25f / den;              // fold 1/HEADS into attn
    for (int k = 0; k < KNB; k++) attn_s[tii][head][k] = sc[k] * inv;
  }
  __syncthreads();
  float ac[NHEADS][KNB];
  for (int hd = 0; hd < NHEADS; hd++)
    for (int k = 0; k < KNB; k++) ac[hd][k] = attn_s[ti][hd][k];
  float y8[8] = {};
  for (int hd = 0; hd < NHEADS; hd++){
    #pragma unroll
    for (int k = 0; k < KNB; k++){
      bf16x8 v = __builtin_bit_cast(bf16x8, *(const uint4*)(&hs[ti + k][hd * DD + c * 8]));
      float a = ac[hd][k];
      #pragma unroll
      for (int e = 0; e < 8; e++) y8[e] += a * (float)v[e];
    }
  }
  float s = 0.f, sq = 0.f;
  #pragma unroll
  for (int e = 0; e < 8; e++){
    float zz = y8[e] + bb[e] + xr[e];
    y8[e] = zz; s += zz; sq += zz * zz;
  }
  part_s[tid] = s; part_q[tid] = sq;
  __syncthreads();
  if (wave < ATPB){
    float vs = part_s[wave * 96 + lane];
    float vq = part_q[wave * 96 + lane];
    if (lane < 32){
      vs += part_s[wave * 96 + 64 + lane];
      vq += part_q[wave * 96 + 64 + lane];
    }
    for (int off = 32; off > 0; off >>= 1){
      vs += __shfl_xor(vs, off, 64);
      vq += __shfl_xor(vq, off, 64);
    }
    if (lane == 0){
      float mean = vs * (1.f / HH);
      float var = vq * (1.f / HH) - mean * mean;
      mv_mean[wave] = mean;
      mv_rstd[wave] = rsqrtf(var + 1e-5f);
    }
  }
  __syncthreads();
  float mean = mv_mean[ti], rstd = mv_rstd[ti];
  float o[8];
  #pragma unroll
  for (int e = 0; e < 8; e++)
    o[e] = (y8[e] - mean) * rstd * gr[e] + br[e];
  if (write_f32){
    float* xo = &x_out[(size_t)token * HH + c * 8];
    *(float4*)&xo[0] = *(float4*)&o[0];
    *(float4*)&xo[4] = *(float4*)&o[4];
  } else {
    unsigned short o16[8];
    #pragma unroll
    for (int e = 0; e < 8; e++) o16[e] = f2bf(o[e]);
    *(uint4*)(&xb_next[(size_t)token * HH + c * 8]) = *(uint4*)&o16[0];
  }
}

extern "C" void kernel_launch(void* const* d_in, const int* in_sizes, int n_in,
                              void* d_out, int out_size, void* d_ws, size_t ws_size,
                              hipStream_t stream) {
  const float* x     = (const float*)d_in[0];
  const float* W     = (const float*)d_in[1];
  const float* a_src = (const float*)d_in[2];
  const float* a_dst = (const float*)d_in[3];
  const float* bias  = (const float*)d_in[4];
  const float* gamma = (const float*)d_in[5];
  const float* beta  = (const float*)d_in[6];
  float* out = (float*)d_out;

  char* ws = (char*)d_ws;
  size_t off = 0;
  auto alloc = [&](size_t bytes)->char*{
    char* p = ws + off;
    off = (off + bytes + 255) & ~(size_t)255;
    return p;
  };
  unsigned short* wt   = (unsigned short*)alloc((size_t)LL * NN * HH * 2);
  unsigned short* xb   = (unsigned short*)alloc((size_t)BT * HH * 2);
  unsigned short* hbuf = (unsigned short*)alloc((size_t)BT * NN * 2);
  float* psrc  = (float*)alloc((size_t)BT * NHEADS * NBLK * 4);
  float* pdst  = (float*)alloc((size_t)BT * NHEADS * NBLK * 4);

  wt_kernel<<<dim3(NN/32, HH/32, LL), dim3(32, 8), 0, stream>>>(W, wt);
  xconv_kernel<<<(BT * HH / 4) / 256, 256, 0, stream>>>(x, xb);

  for (int l = 0; l < LL; l++){
    gemm_kernel<<<(BT / BM) * (NN / BN), 512, 0, stream>>>(
        xb, wt + (size_t)l * NN * HH, hbuf,
        a_src + (size_t)l * NHEADS * DD, a_dst + (size_t)l * NHEADS * DD,
        psrc, pdst);
    attn_ln_kernel<<<BT / ATPB, 384, 0, stream>>>(hbuf, psrc, pdst,
        (l == 0) ? x : nullptr, xb,
        bias + (size_t)l * DD, gamma + (size_t)l * HH, beta + (size_t)l * HH,
        out, xb, (l == LL - 1) ? 1 : 0);
  }
}

// Round 2
// 339.464 us; speedup vs baseline: 1.2914x; 1.2914x over previous
//
#include <hip/hip_runtime.h>
#include <stdint.h>

#define TT 2048
#define BB 4
#define HH 768
#define NHEADS 4
#define DD 768
#define NN 3072   // NHEADS*DD
#define LL 3
#define BT 8192   // BB*TT
#define KNB 5
#define NBLK 12   // 64-col partial blocks per head (DD/64)
#define ATPB 4    // tokens per attn block
#define NROWS 8   // ATPB + KNB - 1 (halo rows in partial-sum window)

typedef __bf16 bf16x8 __attribute__((ext_vector_type(8)));
typedef float f32x4 __attribute__((ext_vector_type(4)));

__device__ __forceinline__ unsigned short f2bf(float f){
  union { float f; unsigned u; } v; v.f = f;
  unsigned u = v.u;
  return (unsigned short)((u + 0x7FFFu + ((u >> 16) & 1u)) >> 16);
}
__device__ __forceinline__ float bf2f(unsigned short h){
  union { unsigned u; float f; } v; v.u = ((unsigned)h) << 16;
  return v.f;
}
// async global->LDS, 16B per lane; LDS dest = wave-uniform base + lane*16
__device__ __forceinline__ void gload16(const unsigned short* g, unsigned short* l){
  __builtin_amdgcn_global_load_lds((const __attribute__((address_space(1))) void*)g,
                                   (__attribute__((address_space(3))) void*)l, 16, 0, 0);
}

// ---------------- W transpose + bf16 convert: W[l][k][n] fp32 -> Wt[l][n][k] bf16
__global__ void wt_kernel(const float* __restrict__ W, unsigned short* __restrict__ Wt){
  __shared__ float tile[32][33];
  int l = blockIdx.z;
  int n0 = blockIdx.x * 32, k0 = blockIdx.y * 32;
  int tx = threadIdx.x, ty = threadIdx.y; // (32,8)
  const float* Wl = W + (size_t)l * HH * NN;
  for (int r = 0; r < 4; r++)
    tile[ty + r*8][tx] = Wl[(size_t)(k0 + ty + r*8) * NN + n0 + tx];
  __syncthreads();
  unsigned short* Wtl = Wt + (size_t)l * NN * HH;
  for (int r = 0; r < 4; r++){
    int n = n0 + ty + r*8;
    Wtl[(size_t)n * HH + k0 + tx] = f2bf(tile[tx][ty + r*8]);
  }
}

// ---------------- x fp32 -> bf16 (layer 0 GEMM input)
__global__ void xconv_kernel(const float* __restrict__ x, unsigned short* __restrict__ xb){
  int i = blockIdx.x * blockDim.x + threadIdx.x;
  float4 v = ((const float4*)x)[i];
  ushort4 o;
  o.x = f2bf(v.x); o.y = f2bf(v.y); o.z = f2bf(v.z); o.w = f2bf(v.w);
  *(ushort4*)(xb + (size_t)i * 4) = o;
}

// ---------------- GEMM (R6 K-loop, frozen) + R11: XCD-aware block remap
// (per-XCD 8-row bm band, bn-major => xb band resident in XCD L2) and
// __launch_bounds__(256,3) to allow 3 co-resident blocks/CU.
// R12 NOTE: a 256x256 8-wave 4-phase port regressed (92us, VGPR at the
// (512,2) cap -> scratch spills corrupted counted-vmcnt waits). Reverted.
#define BM 128
#define BN 128
#define BK 64

__global__ __launch_bounds__(256, 3) void gemm_kernel(
    const unsigned short* __restrict__ xb,
    const unsigned short* __restrict__ wt,
    unsigned short* __restrict__ hout,
    const float* __restrict__ a_srcl,
    const float* __restrict__ a_dstl,
    float* __restrict__ psrc,     // [BT][NHEADS][NBLK]
    float* __restrict__ pdst){
  __shared__ __align__(16) unsigned short xs[BM][BK];   // 16 KB
  __shared__ __align__(16) unsigned short wsd[BN][BK];  // 16 KB
  // XCD-aware remap: hw assigns XCD = blockIdx % 8 (round-robin). Give each
  // XCD a contiguous 8-row bm band; iterate bn-major within the band so the
  // xb band (1.6 MB) stays L2-resident and wt slices (0.2 MB) stream through.
  int id = blockIdx.x;              // 1536
  int xcd = id & 7;
  int s = id >> 3;                  // 0..191
  int bn_i = s / 8;                 // 0..23
  int bm_i = (s & 7) + xcd * 8;     // 0..63
  int bm = bm_i * BM;
  int bn = bn_i * BN;
  int tid = threadIdx.x;
  int wave = tid >> 6, lane = tid & 63;
  int m16 = lane & 15, q = lane >> 4;
  int wm = (wave >> 1) * 64, wn = (wave & 1) * 64;
  int r8 = lane >> 3, c8 = lane & 7;
  int cg = (c8 ^ r8) * 8;     // fetched chunk: position c8 holds global chunk c8^(row&7)
  const unsigned short* ga[4]; const unsigned short* gb[4];
  unsigned short* la[4]; unsigned short* lb[4];
  #pragma unroll
  for (int ss = 0; ss < 4; ss++){
    int row = wave * 32 + ss * 8;
    ga[ss] = xb + (size_t)(bm + row + r8) * HH + cg;
    gb[ss] = wt + (size_t)(bn + row + r8) * HH + cg;
    la[ss] = &xs[row][0];
    lb[ss] = &wsd[row][0];
  }
  int rd0 = ((0 + q) ^ (m16 & 7)) * 8;   // ks=0 fragment chunk offset
  int rd1 = ((4 + q) ^ (m16 & 7)) * 8;   // ks=1
  f32x4 acc[4][4] = {};
  for (int k0 = 0; k0 < HH; k0 += BK){
    #pragma unroll
    for (int ss = 0; ss < 4; ss++){
      gload16(ga[ss] + k0, la[ss]);
      gload16(gb[ss] + k0, lb[ss]);
    }
    __syncthreads();
    bf16x8 af[4], bfr[4];
    for (int i = 0; i < 4; i++)
      af[i] = __builtin_bit_cast(bf16x8, *(const uint4*)(&xs[wm + i*16 + m16][rd0]));
    for (int j = 0; j < 4; j++)
      bfr[j] = __builtin_bit_cast(bf16x8, *(const uint4*)(&wsd[wn + j*16 + m16][rd0]));
    for (int i = 0; i < 4; i++)
      for (int j = 0; j < 4; j++)
        acc[i][j] = __builtin_amdgcn_mfma_f32_16x16x32_bf16(af[i], bfr[j], acc[i][j], 0, 0, 0);
    for (int i = 0; i < 4; i++)
      af[i] = __builtin_bit_cast(bf16x8, *(const uint4*)(&xs[wm + i*16 + m16][rd1]));
    for (int j = 0; j < 4; j++)
      bfr[j] = __builtin_bit_cast(bf16x8, *(const uint4*)(&wsd[wn + j*16 + m16][rd1]));
    for (int i = 0; i < 4; i++)
      for (int j = 0; j < 4; j++)
        acc[i][j] = __builtin_amdgcn_mfma_f32_16x16x32_bf16(af[i], bfr[j], acc[i][j], 0, 0, 0);
    __syncthreads();
  }
  // C store (bf16)
  for (int i = 0; i < 4; i++){
    int row0 = bm + wm + i*16 + q*4;
    for (int j = 0; j < 4; j++){
      int col = bn + wn + j*16 + m16;
      unsigned short* hp = hout + (size_t)row0 * NN + col;
      hp[0]            = f2bf(acc[i][j][0]);
      hp[NN]           = f2bf(acc[i][j][1]);
      hp[2*(size_t)NN] = f2bf(acc[i][j][2]);
      hp[3*(size_t)NN] = f2bf(acc[i][j][3]);
    }
  }
  // fused asrc/adst partials: wave covers 64 cols = one (head, blk) slot
  int col0 = bn + wn;
  int head = col0 / DD;
  int blk  = (col0 % DD) >> 6;
  float wsrc[4], wdstw[4];
  for (int j = 0; j < 4; j++){
    int n = col0 + j*16 + m16;
    wsrc[j]  = a_srcl[n];
    wdstw[j] = a_dstl[n];
  }
  for (int i = 0; i < 4; i++){
    for (int reg = 0; reg < 4; reg++){
      float ss = 0.f, dd = 0.f;
      for (int j = 0; j < 4; j++){
        float v = acc[i][j][reg];
        ss += v * wsrc[j];
        dd += v * wdstw[j];
      }
      ss += __shfl_xor(ss, 1, 64); dd += __shfl_xor(dd, 1, 64);
      ss += __shfl_xor(ss, 2, 64); dd += __shfl_xor(dd, 2, 64);
      ss += __shfl_xor(ss, 4, 64); dd += __shfl_xor(dd, 4, 64);
      ss += __shfl_xor(ss, 8, 64); dd += __shfl_xor(dd, 8, 64);
      if (m16 == 0){
        int row = bm + wm + i*16 + q*4 + reg;
        size_t slot = (size_t)row * (NHEADS * NBLK) + head * NBLK + blk;
        psrc[slot] = ss;
        pdst[slot] = dd;
      }
    }
  }
}

// ---------------- attention + head-mean + bias + residual + layernorm
// R13: no LDS staging of h (48 KB/block is L1/L2-resident; staging drain +
// LDS round-trip was the critical path). h read directly from global in the
// PV loop (coalesced 16B/lane). Softmax computed redundantly per-thread
// (20 __expf) -> removes the 16-thread serial section and one barrier.
// LDS 61 KB -> ~3.4 KB; barriers 4 -> 3.
__global__ __launch_bounds__(384) void attn_ln_kernel(const unsigned short* __restrict__ h,
    const float* __restrict__ psrc, const float* __restrict__ pdst,
    const float* __restrict__ xin_f32,          // non-null => layer 0 residual (fp32)
    const unsigned short* __restrict__ xin_bf,  // else residual from bf16 xb
    const float* __restrict__ bias_l,
    const float* __restrict__ gamma_l, const float* __restrict__ beta_l,
    float* __restrict__ x_out, unsigned short* __restrict__ xb_next,
    int write_f32){
  int bid = blockIdx.x;                       // 2048
  int grp = ((bid & 7) << 8) | (bid >> 3);    // XCD-contiguous groups
  int token0 = grp * ATPB;
  int t0 = token0 & (TT - 1);
  int bseq = token0 >> 11;
  int tid = threadIdx.x;
  int wave = tid >> 6, lane = tid & 63;
  int ti = tid / 96, c = tid % 96;            // token-in-block, 8-elem chunk
  int token = token0 + ti;
  __shared__ float as_sh[NROWS * NHEADS], ad_sh[NROWS * NHEADS];
  __shared__ float part_s[ATPB * 96], part_q[ATPB * 96];
  __shared__ float mv_mean[ATPB], mv_rstd[ATPB];

  // srcred: 64 threads sum the window tokens' 12-blk partials into LDS
  if (tid < 2 * NROWS * NHEADS){     // 64
    int which = tid >= NROWS * NHEADS;
    int i = tid & (NROWS * NHEADS - 1);
    int lt = i >> 2, head = i & 3;
    int tcl = min(max(t0 - 2 + lt, 0), TT - 1);
    const float* p = (which ? pdst : psrc) +
        ((size_t)(bseq * TT + tcl) * NHEADS + head) * NBLK;
    float4 a = *(const float4*)(p);
    float4 b = *(const float4*)(p + 4);
    float4 d = *(const float4*)(p + 8);
    float s = a.x+a.y+a.z+a.w + b.x+b.y+b.z+b.w + d.x+d.y+d.z+d.w;
    (which ? ad_sh : as_sh)[i] = s;
  }

  // hs-independent global loads (overlap the srcred)
  float xr[8], bb[8], gr[8], br[8];
  if (xin_f32){
    const float4* p = (const float4*)&xin_f32[(size_t)token * HH + c * 8];
    *(float4*)&xr[0] = p[0]; *(float4*)&xr[4] = p[1];
  } else {
    uint4 u = *(const uint4*)&xin_bf[(size_t)token * HH + c * 8];
    const unsigned short* us = (const unsigned short*)&u;
    #pragma unroll
    for (int e = 0; e < 8; e++) xr[e] = bf2f(us[e]);
  }
  { const float4* p = (const float4*)&bias_l[c * 8];
    *(float4*)&bb[0] = p[0]; *(float4*)&bb[4] = p[1]; }
  { const float4* p = (const float4*)&gamma_l[c * 8];
    *(float4*)&gr[0] = p[0]; *(float4*)&gr[4] = p[1]; }
  { const float4* p = (const float4*)&beta_l[c * 8];
    *(float4*)&br[0] = p[0]; *(float4*)&br[4] = p[1]; }
  __syncthreads();   // publish as_sh/ad_sh (no DMA drain behind this)

  // per-thread softmax for this token, all 4 heads (redundant across c)
  float aw[NHEADS][KNB];
  #pragma unroll
  for (int hd = 0; hd < NHEADS; hd++){
    float ad = ad_sh[(ti + 2) * NHEADS + hd];
    float sc[KNB];
    float mx = -3.0e38f;
    #pragma unroll
    for (int k = 0; k < KNB; k++){
      int tn = t0 + ti + k - 2;
      if (tn >= 0 && tn < TT){
        float s = as_sh[(ti + k) * NHEADS + hd] + ad;
        s = s > 0.f ? s : 0.2f * s;       // leaky_relu 0.2
        sc[k] = s; mx = fmaxf(mx, s);
      } else sc[k] = -3.0e38f;
    }
    float den = 0.f;
    #pragma unroll
    for (int k = 0; k < KNB; k++){
      float e = (sc[k] > -1.0e38f) ? __expf(sc[k] - mx) : 0.f;
      sc[k] = e; den += e;
    }
    float inv = 0.25f / den;              // fold 1/HEADS into attn
    #pragma unroll
    for (int k = 0; k < KNB; k++) aw[hd][k] = sc[k] * inv;
  }

  // PV: read h rows directly from global (L1/L2-resident; halo shared with
  // neighbor blocks). Coalesced: consecutive c => consecutive 16B chunks.
  const unsigned short* hbase = h + (size_t)(bseq * TT) * NN + c * 8;
  float y8[8] = {};
  #pragma unroll
  for (int k = 0; k < KNB; k++){
    int g = t0 + ti + k - 2;
    g = min(max(g, 0), TT - 1);
    const unsigned short* hr = hbase + (size_t)g * NN;
    #pragma unroll
    for (int hd = 0; hd < NHEADS; hd++){
      bf16x8 v = __builtin_bit_cast(bf16x8, *(const uint4*)(hr + hd * DD));
      float a = aw[hd][k];
      #pragma unroll
      for (int e = 0; e < 8; e++) y8[e] += a * (float)v[e];
    }
  }
  float s = 0.f, sq = 0.f;
  #pragma unroll
  for (int e = 0; e < 8; e++){
    float zz = y8[e] + bb[e] + xr[e];
    y8[e] = zz; s += zz; sq += zz * zz;
  }
  part_s[tid] = s; part_q[tid] = sq;
  __syncthreads();
  if (wave < ATPB){
    float vs = part_s[wave * 96 + lane];
    float vq = part_q[wave * 96 + lane];
    if (lane < 32){
      vs += part_s[wave * 96 + 64 + lane];
      vq += part_q[wave * 96 + 64 + lane];
    }
    for (int off = 32; off > 0; off >>= 1){
      vs += __shfl_xor(vs, off, 64);
      vq += __shfl_xor(vq, off, 64);
    }
    if (lane == 0){
      float mean = vs * (1.f / HH);
      float var = vq * (1.f / HH) - mean * mean;
      mv_mean[wave] = mean;
      mv_rstd[wave] = rsqrtf(var + 1e-5f);
    }
  }
  __syncthreads();
  float mean = mv_mean[ti], rstd = mv_rstd[ti];
  float o[8];
  #pragma unroll
  for (int e = 0; e < 8; e++)
    o[e] = (y8[e] - mean) * rstd * gr[e] + br[e];
  if (write_f32){
    float* xo = &x_out[(size_t)token * HH + c * 8];
    *(float4*)&xo[0] = *(float4*)&o[0];
    *(float4*)&xo[4] = *(float4*)&o[4];
  } else {
    unsigned short o16[8];
    #pragma unroll
    for (int e = 0; e < 8; e++) o16[e] = f2bf(o[e]);
    *(uint4*)(&xb_next[(size_t)token * HH + c * 8]) = *(uint4*)&o16[0];
  }
}

extern "C" void kernel_launch(void* const* d_in, const int* in_sizes, int n_in,
                              void* d_out, int out_size, void* d_ws, size_t ws_size,
                              hipStream_t stream) {
  const float* x     = (const float*)d_in[0];
  const float* W     = (const float*)d_in[1];
  const float* a_src = (const float*)d_in[2];
  const float* a_dst = (const float*)d_in[3];
  const float* bias  = (const float*)d_in[4];
  const float* gamma = (const float*)d_in[5];
  const float* beta  = (const float*)d_in[6];
  float* out = (float*)d_out;

  char* ws = (char*)d_ws;
  size_t off = 0;
  auto alloc = [&](size_t bytes)->char*{
    char* p = ws + off;
    off = (off + bytes + 255) & ~(size_t)255;
    return p;
  };
  unsigned short* wt   = (unsigned short*)alloc((size_t)LL * NN * HH * 2);
  unsigned short* xb   = (unsigned short*)alloc((size_t)BT * HH * 2);
  unsigned short* hbuf = (unsigned short*)alloc((size_t)BT * NN * 2);
  float* psrc  = (float*)alloc((size_t)BT * NHEADS * NBLK * 4);
  float* pdst  = (float*)alloc((size_t)BT * NHEADS * NBLK * 4);

  wt_kernel<<<dim3(NN/32, HH/32, LL), dim3(32, 8), 0, stream>>>(W, wt);
  xconv_kernel<<<(BT * HH / 4) / 256, 256, 0, stream>>>(x, xb);

  for (int l = 0; l < LL; l++){
    gemm_kernel<<<(NN / BN) * (BT / BM), 256, 0, stream>>>(
        xb, wt + (size_t)l * NN * HH, hbuf,
        a_src + (size_t)l * NHEADS * DD, a_dst + (size_t)l * NHEADS * DD,
        psrc, pdst);
    attn_ln_kernel<<<BT / ATPB, 384, 0, stream>>>(hbuf, psrc, pdst,
        (l == 0) ? x : nullptr, xb,
        bias + (size_t)l * DD, gamma + (size_t)l * HH, beta + (size_t)l * HH,
        out, xb, (l == LL - 1) ? 1 : 0);
  }
}

// Round 3
// 324.605 us; speedup vs baseline: 1.3506x; 1.0458x over previous
//
#include <hip/hip_runtime.h>
#include <stdint.h>

#define TT 2048
#define BB 4
#define HH 768
#define NHEADS 4
#define DD 768
#define NN 3072   // NHEADS*DD
#define LL 3
#define BT 8192   // BB*TT
#define KNB 5
#define NBLK 12   // 64-col partial blocks per head (DD/64)

typedef __bf16 bf16x8 __attribute__((ext_vector_type(8)));
typedef float f32x4 __attribute__((ext_vector_type(4)));

__device__ __forceinline__ unsigned short f2bf(float f){
  union { float f; unsigned u; } v; v.f = f;
  unsigned u = v.u;
  return (unsigned short)((u + 0x7FFFu + ((u >> 16) & 1u)) >> 16);
}
__device__ __forceinline__ float bf2f(unsigned short h){
  union { unsigned u; float f; } v; v.u = ((unsigned)h) << 16;
  return v.f;
}
// async global->LDS, 16B per lane; LDS dest = wave-uniform base + lane*16
__device__ __forceinline__ void gload16(const unsigned short* g, unsigned short* l){
  __builtin_amdgcn_global_load_lds((const __attribute__((address_space(1))) void*)g,
                                   (__attribute__((address_space(3))) void*)l, 16, 0, 0);
}

// ---------------- W transpose + bf16 convert: W[l][k][n] fp32 -> Wt[l][n][k] bf16
__global__ void wt_kernel(const float* __restrict__ W, unsigned short* __restrict__ Wt){
  __shared__ float tile[32][33];
  int l = blockIdx.z;
  int n0 = blockIdx.x * 32, k0 = blockIdx.y * 32;
  int tx = threadIdx.x, ty = threadIdx.y; // (32,8)
  const float* Wl = W + (size_t)l * HH * NN;
  for (int r = 0; r < 4; r++)
    tile[ty + r*8][tx] = Wl[(size_t)(k0 + ty + r*8) * NN + n0 + tx];
  __syncthreads();
  unsigned short* Wtl = Wt + (size_t)l * NN * HH;
  for (int r = 0; r < 4; r++){
    int n = n0 + ty + r*8;
    Wtl[(size_t)n * HH + k0 + tx] = f2bf(tile[tx][ty + r*8]);
  }
}

// ---------------- x fp32 -> bf16 (layer 0 GEMM input)
__global__ void xconv_kernel(const float* __restrict__ x, unsigned short* __restrict__ xb){
  int i = blockIdx.x * blockDim.x + threadIdx.x;
  float4 v = ((const float4*)x)[i];
  ushort4 o;
  o.x = f2bf(v.x); o.y = f2bf(v.y); o.z = f2bf(v.z); o.w = f2bf(v.w);
  *(ushort4*)(xb + (size_t)i * 4) = o;
}

// ---------------- GEMM (R6 K-loop, frozen) + R11: XCD-aware block remap
// (per-XCD 8-row bm band, bn-major => xb band resident in XCD L2) and
// __launch_bounds__(256,3) to allow 3 co-resident blocks/CU.
// R12 NOTE: a 256x256 8-wave 4-phase port regressed (92us, VGPR at the
// (512,2) cap -> scratch spills corrupted counted-vmcnt waits). Reverted.
#define BM 128
#define BN 128
#define BK 64

__global__ __launch_bounds__(256, 3) void gemm_kernel(
    const unsigned short* __restrict__ xb,
    const unsigned short* __restrict__ wt,
    unsigned short* __restrict__ hout,
    const float* __restrict__ a_srcl,
    const float* __restrict__ a_dstl,
    float* __restrict__ psrc,     // [BT][NHEADS][NBLK]
    float* __restrict__ pdst){
  __shared__ __align__(16) unsigned short xs[BM][BK];   // 16 KB
  __shared__ __align__(16) unsigned short wsd[BN][BK];  // 16 KB
  // XCD-aware remap: hw assigns XCD = blockIdx % 8 (round-robin). Give each
  // XCD a contiguous 8-row bm band; iterate bn-major within the band so the
  // xb band (1.6 MB) stays L2-resident and wt slices (0.2 MB) stream through.
  int id = blockIdx.x;              // 1536
  int xcd = id & 7;
  int s = id >> 3;                  // 0..191
  int bn_i = s / 8;                 // 0..23
  int bm_i = (s & 7) + xcd * 8;     // 0..63
  int bm = bm_i * BM;
  int bn = bn_i * BN;
  int tid = threadIdx.x;
  int wave = tid >> 6, lane = tid & 63;
  int m16 = lane & 15, q = lane >> 4;
  int wm = (wave >> 1) * 64, wn = (wave & 1) * 64;
  int r8 = lane >> 3, c8 = lane & 7;
  int cg = (c8 ^ r8) * 8;     // fetched chunk: position c8 holds global chunk c8^(row&7)
  const unsigned short* ga[4]; const unsigned short* gb[4];
  unsigned short* la[4]; unsigned short* lb[4];
  #pragma unroll
  for (int ss = 0; ss < 4; ss++){
    int row = wave * 32 + ss * 8;
    ga[ss] = xb + (size_t)(bm + row + r8) * HH + cg;
    gb[ss] = wt + (size_t)(bn + row + r8) * HH + cg;
    la[ss] = &xs[row][0];
    lb[ss] = &wsd[row][0];
  }
  int rd0 = ((0 + q) ^ (m16 & 7)) * 8;   // ks=0 fragment chunk offset
  int rd1 = ((4 + q) ^ (m16 & 7)) * 8;   // ks=1
  f32x4 acc[4][4] = {};
  for (int k0 = 0; k0 < HH; k0 += BK){
    #pragma unroll
    for (int ss = 0; ss < 4; ss++){
      gload16(ga[ss] + k0, la[ss]);
      gload16(gb[ss] + k0, lb[ss]);
    }
    __syncthreads();
    bf16x8 af[4], bfr[4];
    for (int i = 0; i < 4; i++)
      af[i] = __builtin_bit_cast(bf16x8, *(const uint4*)(&xs[wm + i*16 + m16][rd0]));
    for (int j = 0; j < 4; j++)
      bfr[j] = __builtin_bit_cast(bf16x8, *(const uint4*)(&wsd[wn + j*16 + m16][rd0]));
    for (int i = 0; i < 4; i++)
      for (int j = 0; j < 4; j++)
        acc[i][j] = __builtin_amdgcn_mfma_f32_16x16x32_bf16(af[i], bfr[j], acc[i][j], 0, 0, 0);
    for (int i = 0; i < 4; i++)
      af[i] = __builtin_bit_cast(bf16x8, *(const uint4*)(&xs[wm + i*16 + m16][rd1]));
    for (int j = 0; j < 4; j++)
      bfr[j] = __builtin_bit_cast(bf16x8, *(const uint4*)(&wsd[wn + j*16 + m16][rd1]));
    for (int i = 0; i < 4; i++)
      for (int j = 0; j < 4; j++)
        acc[i][j] = __builtin_amdgcn_mfma_f32_16x16x32_bf16(af[i], bfr[j], acc[i][j], 0, 0, 0);
    __syncthreads();
  }
  // C store (bf16)
  for (int i = 0; i < 4; i++){
    int row0 = bm + wm + i*16 + q*4;
    for (int j = 0; j < 4; j++){
      int col = bn + wn + j*16 + m16;
      unsigned short* hp = hout + (size_t)row0 * NN + col;
      hp[0]            = f2bf(acc[i][j][0]);
      hp[NN]           = f2bf(acc[i][j][1]);
      hp[2*(size_t)NN] = f2bf(acc[i][j][2]);
      hp[3*(size_t)NN] = f2bf(acc[i][j][3]);
    }
  }
  // fused asrc/adst partials: wave covers 64 cols = one (head, blk) slot
  int col0 = bn + wn;
  int head = col0 / DD;
  int blk  = (col0 % DD) >> 6;
  float wsrc[4], wdstw[4];
  for (int j = 0; j < 4; j++){
    int n = col0 + j*16 + m16;
    wsrc[j]  = a_srcl[n];
    wdstw[j] = a_dstl[n];
  }
  for (int i = 0; i < 4; i++){
    for (int reg = 0; reg < 4; reg++){
      float ss = 0.f, dd = 0.f;
      for (int j = 0; j < 4; j++){
        float v = acc[i][j][reg];
        ss += v * wsrc[j];
        dd += v * wdstw[j];
      }
      ss += __shfl_xor(ss, 1, 64); dd += __shfl_xor(dd, 1, 64);
      ss += __shfl_xor(ss, 2, 64); dd += __shfl_xor(dd, 2, 64);
      ss += __shfl_xor(ss, 4, 64); dd += __shfl_xor(dd, 4, 64);
      ss += __shfl_xor(ss, 8, 64); dd += __shfl_xor(dd, 8, 64);
      if (m16 == 0){
        int row = bm + wm + i*16 + q*4 + reg;
        size_t slot = (size_t)row * (NHEADS * NBLK) + head * NBLK + blk;
        psrc[slot] = ss;
        pdst[slot] = dd;
      }
    }
  }
}

// ---------------- attention + head-mean + bias + residual + layernorm
// R14: one wave per token, ZERO barriers, ZERO LDS. HH=768 = 64 lanes x 12
// elems (3 groups of 4 at lane*4 + j*256 -> all global accesses coalesced).
// srcred partials live in lanes 0..23, gathered via __shfl (v_readlane);
// LayerNorm is a 6-step __shfl_xor wave reduce. Waves fully independent ->
// latency hidden by TLP alone, occupancy bounded only by VGPR.
__global__ __launch_bounds__(512) void attn_ln_kernel(const unsigned short* __restrict__ h,
    const float* __restrict__ psrc, const float* __restrict__ pdst,
    const float* __restrict__ xin_f32,          // non-null => layer 0 residual (fp32)
    const unsigned short* __restrict__ xin_bf,  // else residual from bf16 xb
    const float* __restrict__ bias_l,
    const float* __restrict__ gamma_l, const float* __restrict__ beta_l,
    float* __restrict__ x_out, unsigned short* __restrict__ xb_next,
    int write_f32){
  int bid = blockIdx.x;                       // 1024 blocks x 8 waves
  int grp = ((bid & 7) << 7) | (bid >> 3);    // XCD-contiguous 1024-token bands
  int wave = threadIdx.x >> 6, lane = threadIdx.x & 63;
  int token = grp * 8 + wave;
  int t = token & (TT - 1);
  int bseq = token >> 11;

  // srcred: lanes 0..19 hold as[k][hd] (window row k=lane>>2, head=lane&3);
  // lanes 20..23 hold ad[hd] for this token. Each sums 12 partial floats.
  float red = 0.f;
  if (lane < 24){
    const float* p;
    if (lane < 20){
      int k = lane >> 2, hd = lane & 3;
      int row = min(max(t - 2 + k, 0), TT - 1);
      p = psrc + ((size_t)(bseq * TT + row) * NHEADS + hd) * NBLK;
    } else {
      int hd = lane - 20;
      p = pdst + ((size_t)(bseq * TT + t) * NHEADS + hd) * NBLK;
    }
    float4 a = *(const float4*)(p);
    float4 b = *(const float4*)(p + 4);
    float4 d = *(const float4*)(p + 8);
    red = a.x+a.y+a.z+a.w + b.x+b.y+b.z+b.w + d.x+d.y+d.z+d.w;
  }

  // per-head softmax (redundant across lanes; shfl with uniform idx ~ free)
  // + PV accumulate. Lane owns elems lane*4 + j*256, j=0..2.
  const unsigned short* hb = h + (size_t)(bseq * TT) * NN + lane * 4;
  float y[12] = {};
  #pragma unroll
  for (int hd = 0; hd < NHEADS; hd++){
    float ad = __shfl(red, 20 + hd, 64);
    float sc[KNB];
    float mx = -3.0e38f;
    #pragma unroll
    for (int k = 0; k < KNB; k++){
      int tn = t + k - 2;                 // wave-uniform branch
      if (tn >= 0 && tn < TT){
        float s = __shfl(red, k * 4 + hd, 64) + ad;
        s = s > 0.f ? s : 0.2f * s;       // leaky_relu 0.2
        sc[k] = s; mx = fmaxf(mx, s);
      } else sc[k] = -3.0e38f;
    }
    float den = 0.f;
    #pragma unroll
    for (int k = 0; k < KNB; k++){
      float e = (sc[k] > -1.0e38f) ? __expf(sc[k] - mx) : 0.f;
      sc[k] = e; den += e;
    }
    float inv = 0.25f / den;              // fold 1/HEADS into attn
    #pragma unroll
    for (int k = 0; k < KNB; k++){
      int g = t + k - 2;
      g = min(max(g, 0), TT - 1);
      const unsigned short* hr = hb + (size_t)g * NN + hd * DD;
      float a = sc[k] * inv;
      #pragma unroll
      for (int j = 0; j < 3; j++){
        uint2 u = *(const uint2*)(hr + j * 256);
        const unsigned short* us = (const unsigned short*)&u;
        y[j*4+0] += a * bf2f(us[0]);
        y[j*4+1] += a * bf2f(us[1]);
        y[j*4+2] += a * bf2f(us[2]);
        y[j*4+3] += a * bf2f(us[3]);
      }
    }
  }

  // residual + bias, accumulate LN stats
  float xr[12], bb[12];
  if (xin_f32){
    const float* xp = xin_f32 + (size_t)token * HH + lane * 4;
    #pragma unroll
    for (int j = 0; j < 3; j++) *(float4*)&xr[j*4] = *(const float4*)(xp + j * 256);
  } else {
    const unsigned short* xp = xin_bf + (size_t)token * HH + lane * 4;
    #pragma unroll
    for (int j = 0; j < 3; j++){
      uint2 u = *(const uint2*)(xp + j * 256);
      const unsigned short* us = (const unsigned short*)&u;
      xr[j*4+0] = bf2f(us[0]); xr[j*4+1] = bf2f(us[1]);
      xr[j*4+2] = bf2f(us[2]); xr[j*4+3] = bf2f(us[3]);
    }
  }
  { const float* p = bias_l + lane * 4;
    #pragma unroll
    for (int j = 0; j < 3; j++) *(float4*)&bb[j*4] = *(const float4*)(p + j * 256); }
  float s = 0.f, sq = 0.f;
  #pragma unroll
  for (int e = 0; e < 12; e++){
    float zz = y[e] + bb[e] + xr[e];
    y[e] = zz; s += zz; sq += zz * zz;
  }
  // wave-level LN reduce (no LDS, no barrier)
  #pragma unroll
  for (int off = 32; off > 0; off >>= 1){
    s  += __shfl_xor(s, off, 64);
    sq += __shfl_xor(sq, off, 64);
  }
  float mean = s * (1.f / HH);
  float var = sq * (1.f / HH) - mean * mean;
  float rstd = rsqrtf(var + 1e-5f);

  float gr[12], br[12];
  { const float* p = gamma_l + lane * 4;
    #pragma unroll
    for (int j = 0; j < 3; j++) *(float4*)&gr[j*4] = *(const float4*)(p + j * 256); }
  { const float* p = beta_l + lane * 4;
    #pragma unroll
    for (int j = 0; j < 3; j++) *(float4*)&br[j*4] = *(const float4*)(p + j * 256); }

  float o[12];
  #pragma unroll
  for (int e = 0; e < 12; e++)
    o[e] = (y[e] - mean) * rstd * gr[e] + br[e];

  if (write_f32){
    float* xo = x_out + (size_t)token * HH + lane * 4;
    #pragma unroll
    for (int j = 0; j < 3; j++) *(float4*)(xo + j * 256) = *(float4*)&o[j*4];
  } else {
    unsigned short* xo = xb_next + (size_t)token * HH + lane * 4;
    #pragma unroll
    for (int j = 0; j < 3; j++){
      ushort4 o16;
      o16.x = f2bf(o[j*4+0]); o16.y = f2bf(o[j*4+1]);
      o16.z = f2bf(o[j*4+2]); o16.w = f2bf(o[j*4+3]);
      *(ushort4*)(xo + j * 256) = o16;
    }
  }
}

extern "C" void kernel_launch(void* const* d_in, const int* in_sizes, int n_in,
                              void* d_out, int out_size, void* d_ws, size_t ws_size,
                              hipStream_t stream) {
  const float* x     = (const float*)d_in[0];
  const float* W     = (const float*)d_in[1];
  const float* a_src = (const float*)d_in[2];
  const float* a_dst = (const float*)d_in[3];
  const float* bias  = (const float*)d_in[4];
  const float* gamma = (const float*)d_in[5];
  const float* beta  = (const float*)d_in[6];
  float* out = (float*)d_out;

  char* ws = (char*)d_ws;
  size_t off = 0;
  auto alloc = [&](size_t bytes)->char*{
    char* p = ws + off;
    off = (off + bytes + 255) & ~(size_t)255;
    return p;
  };
  unsigned short* wt   = (unsigned short*)alloc((size_t)LL * NN * HH * 2);
  unsigned short* xb   = (unsigned short*)alloc((size_t)BT * HH * 2);
  unsigned short* hbuf = (unsigned short*)alloc((size_t)BT * NN * 2);
  float* psrc  = (float*)alloc((size_t)BT * NHEADS * NBLK * 4);
  float* pdst  = (float*)alloc((size_t)BT * NHEADS * NBLK * 4);

  wt_kernel<<<dim3(NN/32, HH/32, LL), dim3(32, 8), 0, stream>>>(W, wt);
  xconv_kernel<<<(BT * HH / 4) / 256, 256, 0, stream>>>(x, xb);

  for (int l = 0; l < LL; l++){
    gemm_kernel<<<(NN / BN) * (BT / BM), 256, 0, stream>>>(
        xb, wt + (size_t)l * NN * HH, hbuf,
        a_src + (size_t)l * NHEADS * DD, a_dst + (size_t)l * NHEADS * DD,
        psrc, pdst);
    attn_ln_kernel<<<BT / 8, 512, 0, stream>>>(hbuf, psrc, pdst,
        (l == 0) ? x : nullptr, xb,
        bias + (size_t)l * DD, gamma + (size_t)l * HH, beta + (size_t)l * HH,
        out, xb, (l == LL - 1) ? 1 : 0);
  }
}